// Round 7
// baseline (293.921 us; speedup 1.0000x reference)
//
#include <hip/hip_runtime.h>
#include <hip/hip_bf16.h>

#define B_    64
#define HFS   56
#define CIN   96
#define NQ    785
#define NK    197
#define QW    28
#define KW    14
#define NTOT  3137    // 56*56+1
#define NQP   800     // q tokens padded to 16
#define NKP   208     // kv tokens padded to 16
#define NKPV  224     // PV K-dim padded to 32
#define VROWS 112     // 96 v channels + ones row + 15 zero rows
#define KSCL  0.10206207261596575f   // 96^-0.5, folded into Wk

typedef __attribute__((ext_vector_type(8))) short short8;
typedef __attribute__((ext_vector_type(4))) short shortx4;
typedef __attribute__((ext_vector_type(4))) float floatx4;

__device__ __forceinline__ short f2s(float x) {
    __hip_bfloat16 h = __float2bfloat16(x);
    return *reinterpret_cast<short*>(&h);
}
__device__ __forceinline__ float s2f(short s) {
    __hip_bfloat16 h; *reinterpret_cast<short*>(&h) = s;
    return __bfloat162float(h);
}
__device__ __forceinline__ short8 ld8(const short* p) {
    return *reinterpret_cast<const short8*>(p);
}

#define MFMA16(a,b,c) __builtin_amdgcn_mfma_f32_16x16x32_bf16((a),(b),(c),0,0,0)

// ---------------------------------------------------------------------------
// Kernel 0: prep = repack W^T (bf16; Wk pre-scaled), rel matrix, vt pad init,
// and conv-weight transposes cwT[9][96] (fp32, coalesced reads in pool).
// ---------------------------------------------------------------------------
__global__ void prep_kernel(const float* __restrict__ Wq, const float* __restrict__ Wk,
                            const float* __restrict__ Wv, const float* __restrict__ relh,
                            const float* __restrict__ relw,
                            const float* __restrict__ pqw, const float* __restrict__ pkw,
                            const float* __restrict__ pvw,
                            short* __restrict__ WTq, short* __restrict__ WTk,
                            short* __restrict__ WTv, short* __restrict__ relc,
                            short* __restrict__ vt,
                            float* __restrict__ cwqT, float* __restrict__ cwkT,
                            float* __restrict__ cwvT)
{
    int i = blockIdx.x * 256 + threadIdx.x;           // 724000 total
    if (i < 18432)      { int o = i/96, c = i%96;              WTq[o*96+c] = f2s(Wq[c*192+o]); }
    else if (i < 36864) { int j = i-18432; int o=j/96,c=j%96;  WTk[o*96+c] = f2s(Wk[c*192+o]*KSCL); }
    else if (i < 55296) { int j = i-36864; int o=j/96,c=j%96;  WTv[o*96+c] = f2s(Wv[c*192+o]); }
    else if (i < 66048) {
        int j = i - 55296;  int r = j/96, c = j%96;            // 112*96
        float v = (r < 54) ? relh[r*96+c] : ((r < 108) ? relw[(r-54)*96+c] : 0.f);
        relc[r*96+c] = f2s(v);
    } else if (i < 721408) {
        int j2 = i - 66048;                                     // 128 * 5120
        int bh = j2 / 5120, r = j2 % 5120;
        int row, tok; short val;
        if (r < 3584) { row = 96 + r/224; tok = r%224;
                        val = (row == 96 && tok < NK) ? (short)0x3F80 : (short)0; }
        else          { int rr = r-3584; row = rr/16; tok = 208 + (rr%16); val = 0; }
        vt[((long)bh*VROWS + row)*NKPV + tok] = val;
    } else if (i < 724000) {
        int j = i - 721408;                                     // 3 * 864
        int w = j / 864, r = j % 864;
        int c = r / 9, off = r % 9;
        const float* src = (w == 0) ? pqw : (w == 1) ? pkw : pvw;
        float*       dst = (w == 0) ? cwqT : (w == 1) ? cwkT : cwvT;
        dst[off*96 + c] = src[c*9 + off];
    }
}

// ---------------------------------------------------------------------------
// Kernel 1: FUSED depthwise pool conv + LayerNorm + MFMA projection.
// Block = 4 waves = one 16-token tile. Phase 1: each wave convs 4 tokens
// (lanes 0..47 x 2 channels), LN, writes bf16 rows to LDS tile. Phase 2:
// MFMA proj from LDS tile (q/k swapped orient, v original into vt^T).
// ---------------------------------------------------------------------------
__global__ __launch_bounds__(256) void pool_proj_kernel(
    const float* __restrict__ hs,
    const float* __restrict__ cwqT, const float* __restrict__ cwkT, const float* __restrict__ cwvT,
    const float* __restrict__ gq, const float* __restrict__ betaq,
    const float* __restrict__ gk, const float* __restrict__ betak,
    const float* __restrict__ gv, const float* __restrict__ betav,
    const short* __restrict__ WTq, const short* __restrict__ WTk, const short* __restrict__ WTv,
    const float* __restrict__ bq, const float* __restrict__ bk, const float* __restrict__ bv,
    short* __restrict__ qb, short* __restrict__ kb, short* __restrict__ vt)
{
    __shared__ short tiles[2][16][96];

    int tid  = threadIdx.x;
    int w    = tid >> 6;
    int lane = tid & 63;
    int quad = lane >> 4, col = lane & 15;
    bool act = (lane < 48);
    int c = lane * 2;

    int blk = blockIdx.x;                 // 3200 q-blocks + 832 kv-blocks
    bool qmode = (blk < 3200);
    int b, t0;
    if (qmode) { b = blk / 50; t0 = (blk % 50) * 16; }
    else       { int r = blk - 3200; b = r / 13; t0 = (r % 13) * 16; }
    const long hb = (long)b * NTOT * CIN;

    if (qmode) {
        float2 w2[9];
        if (act) {
            #pragma unroll
            for (int o = 0; o < 9; ++o)
                w2[o] = *reinterpret_cast<const float2*>(cwqT + o*96 + c);
        }
        float xa[4], xb[4];
        #pragma unroll
        for (int i = 0; i < 4; ++i) {
            xa[i] = 0.f; xb[i] = 0.f;
            int tok = t0 + w*4 + i;       // wave-uniform
            if (tok >= NQ) continue;
            if (tok == 0) {
                if (act) { float2 h2 = *reinterpret_cast<const float2*>(hs + hb + c); xa[i] = h2.x; xb[i] = h2.y; }
                continue;
            }
            int j = tok - 1, oy = j / QW, ox = j % QW;
            #pragma unroll
            for (int dy = 0; dy < 3; ++dy) {
                int iy = oy*2 - 1 + dy;
                if (iy < 0 || iy >= HFS) continue;
                #pragma unroll
                for (int dx = 0; dx < 3; ++dx) {
                    int ix = ox*2 - 1 + dx;
                    if (ix < 0 || ix >= HFS) continue;
                    if (act) {
                        float2 h2 = *reinterpret_cast<const float2*>(hs + hb + (long)(1 + iy*HFS + ix)*CIN + c);
                        xa[i] = fmaf(h2.x, w2[dy*3+dx].x, xa[i]);
                        xb[i] = fmaf(h2.y, w2[dy*3+dx].y, xb[i]);
                    }
                }
            }
        }
        #pragma unroll
        for (int i = 0; i < 4; ++i) {
            int tok = t0 + w*4 + i;
            int rl  = w*4 + i;
            if (tok >= NQ) { if (act) *reinterpret_cast<unsigned*>(&tiles[0][rl][c]) = 0u; continue; }
            float s  = act ? (xa[i] + xb[i]) : 0.f;
            float ss = act ? (xa[i]*xa[i] + xb[i]*xb[i]) : 0.f;
            #pragma unroll
            for (int off = 32; off >= 1; off >>= 1) { s += __shfl_xor(s, off, 64); ss += __shfl_xor(ss, off, 64); }
            float m = s / CIN, var = ss / CIN - m*m, r = rsqrtf(var + 1e-5f);
            if (act) {
                float2 g2 = *reinterpret_cast<const float2*>(gq + c);
                float2 b2 = *reinterpret_cast<const float2*>(betaq + c);
                unsigned pa = (unsigned short)f2s((xa[i]-m)*r*g2.x + b2.x);
                unsigned pb = (unsigned short)f2s((xb[i]-m)*r*g2.y + b2.y);
                *reinterpret_cast<unsigned*>(&tiles[0][rl][c]) = pa | (pb << 16);
            }
        }
    } else {
        float2 wk2[9], wv2[9];
        if (act) {
            #pragma unroll
            for (int o = 0; o < 9; ++o) {
                wk2[o] = *reinterpret_cast<const float2*>(cwkT + o*96 + c);
                wv2[o] = *reinterpret_cast<const float2*>(cwvT + o*96 + c);
            }
        }
        float ka[4], kb2[4], va[4], vb2[4];
        #pragma unroll
        for (int i = 0; i < 4; ++i) {
            ka[i] = 0.f; kb2[i] = 0.f; va[i] = 0.f; vb2[i] = 0.f;
            int tok = t0 + w*4 + i;
            if (tok >= NK) continue;
            if (tok == 0) {
                if (act) {
                    float2 h2 = *reinterpret_cast<const float2*>(hs + hb + c);
                    ka[i] = va[i] = h2.x;  kb2[i] = vb2[i] = h2.y;
                }
                continue;
            }
            int j = tok - 1, oy = j / KW, ox = j % KW;
            #pragma unroll
            for (int dy = 0; dy < 3; ++dy) {
                int iy = oy*4 - 1 + dy;
                if (iy < 0 || iy >= HFS) continue;
                #pragma unroll
                for (int dx = 0; dx < 3; ++dx) {
                    int ix = ox*4 - 1 + dx;
                    if (ix < 0 || ix >= HFS) continue;
                    if (act) {
                        float2 h2 = *reinterpret_cast<const float2*>(hs + hb + (long)(1 + iy*HFS + ix)*CIN + c);
                        int o = dy*3 + dx;
                        ka[i]  = fmaf(h2.x, wk2[o].x, ka[i]);
                        kb2[i] = fmaf(h2.y, wk2[o].y, kb2[i]);
                        va[i]  = fmaf(h2.x, wv2[o].x, va[i]);
                        vb2[i] = fmaf(h2.y, wv2[o].y, vb2[i]);
                    }
                }
            }
        }
        #pragma unroll
        for (int i = 0; i < 4; ++i) {
            int tok = t0 + w*4 + i;
            int rl  = w*4 + i;
            if (tok >= NK) {
                if (act) {
                    *reinterpret_cast<unsigned*>(&tiles[0][rl][c]) = 0u;
                    *reinterpret_cast<unsigned*>(&tiles[1][rl][c]) = 0u;
                }
                continue;
            }
            float s1  = act ? (ka[i] + kb2[i]) : 0.f;
            float ss1 = act ? (ka[i]*ka[i] + kb2[i]*kb2[i]) : 0.f;
            float s2  = act ? (va[i] + vb2[i]) : 0.f;
            float ss2 = act ? (va[i]*va[i] + vb2[i]*vb2[i]) : 0.f;
            #pragma unroll
            for (int off = 32; off >= 1; off >>= 1) {
                s1 += __shfl_xor(s1, off, 64); ss1 += __shfl_xor(ss1, off, 64);
                s2 += __shfl_xor(s2, off, 64); ss2 += __shfl_xor(ss2, off, 64);
            }
            float m1 = s1 / CIN, r1 = rsqrtf(ss1/CIN - m1*m1 + 1e-5f);
            float m2 = s2 / CIN, r2 = rsqrtf(ss2/CIN - m2*m2 + 1e-5f);
            if (act) {
                float2 gk2 = *reinterpret_cast<const float2*>(gk + c);
                float2 bk2 = *reinterpret_cast<const float2*>(betak + c);
                float2 gv2 = *reinterpret_cast<const float2*>(gv + c);
                float2 bv2 = *reinterpret_cast<const float2*>(betav + c);
                unsigned pa = (unsigned short)f2s((ka[i]-m1)*r1*gk2.x + bk2.x);
                unsigned pb = (unsigned short)f2s((kb2[i]-m1)*r1*gk2.y + bk2.y);
                *reinterpret_cast<unsigned*>(&tiles[0][rl][c]) = pa | (pb << 16);
                pa = (unsigned short)f2s((va[i]-m2)*r2*gv2.x + bv2.x);
                pb = (unsigned short)f2s((vb2[i]-m2)*r2*gv2.y + bv2.y);
                *reinterpret_cast<unsigned*>(&tiles[1][rl][c]) = pa | (pb << 16);
            }
        }
    }
    __syncthreads();

    // ---- phase 2: projection MFMA from LDS tile ----
    if (qmode) {
        short8 bt[3];
        #pragma unroll
        for (int cc = 0; cc < 3; ++cc)
            bt[cc] = ld8(&tiles[0][col][cc*32 + quad*8]);
        int tok = t0 + col;
        #pragma unroll
        for (int m2 = 0; m2 < 3; ++m2) {
            int nt = w*3 + m2;
            floatx4 acc = {0.f, 0.f, 0.f, 0.f};
            #pragma unroll
            for (int cc = 0; cc < 3; ++cc) {
                short8 af = ld8(WTq + (nt*16 + col)*96 + cc*32 + quad*8);
                acc = MFMA16(af, bt[cc], acc);
            }
            int o0 = nt*16 + quad*4;
            float4 bo = *reinterpret_cast<const float4*>(bq + o0);
            int h = (o0 >= 96) ? 1 : 0;
            int d0 = o0 - h*96;
            shortx4 val;
            val.x = f2s(acc[0] + bo.x); val.y = f2s(acc[1] + bo.y);
            val.z = f2s(acc[2] + bo.z); val.w = f2s(acc[3] + bo.w);
            *reinterpret_cast<shortx4*>(qb + ((long)(b*2 + h)*NQP + tok)*96 + d0) = val;
        }
    } else {
        short8 btk[3], atv[3];
        #pragma unroll
        for (int cc = 0; cc < 3; ++cc) {
            btk[cc] = ld8(&tiles[0][col][cc*32 + quad*8]);
            atv[cc] = ld8(&tiles[1][col][cc*32 + quad*8]);
        }
        int tok = t0 + col;
        int tl0 = t0 + quad*4;
        #pragma unroll
        for (int m2 = 0; m2 < 3; ++m2) {
            int nt = w*3 + m2;
            // k: swapped orientation -> kb rows
            floatx4 acc = {0.f, 0.f, 0.f, 0.f};
            #pragma unroll
            for (int cc = 0; cc < 3; ++cc) {
                short8 af = ld8(WTk + (nt*16 + col)*96 + cc*32 + quad*8);
                acc = MFMA16(af, btk[cc], acc);
            }
            int o0 = nt*16 + quad*4;
            float4 bo = *reinterpret_cast<const float4*>(bk + o0);
            int h = (o0 >= 96) ? 1 : 0;
            int d0 = o0 - h*96;
            shortx4 val;
            val.x = f2s(acc[0] + bo.x*KSCL); val.y = f2s(acc[1] + bo.y*KSCL);
            val.z = f2s(acc[2] + bo.z*KSCL); val.w = f2s(acc[3] + bo.w*KSCL);
            *reinterpret_cast<shortx4*>(kb + ((long)(b*2 + h)*NKP + tok)*96 + d0) = val;
            // v: original orientation -> vt^T rows
            floatx4 acc2 = {0.f, 0.f, 0.f, 0.f};
            #pragma unroll
            for (int cc = 0; cc < 3; ++cc) {
                short8 bf = ld8(WTv + (nt*16 + col)*96 + cc*32 + quad*8);
                acc2 = MFMA16(atv[cc], bf, acc2);
            }
            int o = nt*16 + col;
            int h2 = (o >= 96) ? 1 : 0;
            int d = o - h2*96;
            float bo1 = bv[o];
            shortx4 vv;
            vv.x = (tl0+0 < NK) ? f2s(acc2[0] + bo1) : (short)0;
            vv.y = (tl0+1 < NK) ? f2s(acc2[1] + bo1) : (short)0;
            vv.z = (tl0+2 < NK) ? f2s(acc2[2] + bo1) : (short)0;
            vv.w = (tl0+3 < NK) ? f2s(acc2[3] + bo1) : (short)0;
            *reinterpret_cast<shortx4*>(vt + ((long)(b*2 + h2)*VROWS + d)*NKPV + tl0) = vv;
        }
    }
}

// ---------------------------------------------------------------------------
// Kernel 2: MFMA attention, one wave per 16-q-row tile, 2 waves/block.
// Per-wave LDS buf[16][260]: cols 0..231 = P (e_s overlaid, dead after
// gather), cols 232..259 = compact rel table eh. Sequence: E-MFMA -> e cols
// 0..111; gather -> eh; fused S-MFMA + bias + exp -> P; PV (+ones row sums).
// ---------------------------------------------------------------------------
__global__ __launch_bounds__(128) void attn_kernel(
    const short* __restrict__ qb, const short* __restrict__ kb,
    const short* __restrict__ vt, const short* __restrict__ relc,
    float* __restrict__ out)
{
    __shared__ short buf[2][16][260];     // 16.25 KB -> 9 blocks/CU

    int tid  = threadIdx.x;
    int wid  = tid >> 6;
    int lane = tid & 63;
    int quad = lane >> 4, col = lane & 15;

    int bid = blockIdx.x;                 // 3200 = 8 * 400
    int tb  = (bid & 7) * 400 + (bid >> 3);
    int wt  = tb * 2 + wid;
    int bh  = wt / 50;
    int t   = wt % 50;
    int q0  = t * 16;
    short (*W)[260] = buf[wid];

    // Q A-fragments
    const short* qrow = qb + ((long)bh*NQP + q0)*96;
    short8 aq[3];
    #pragma unroll
    for (int c = 0; c < 3; ++c)
        aq[c] = ld8(qrow + col*96 + c*32 + quad*8);

    // E = Q Rel^T  -> cols 0..111 (overlaid on P region)
    #pragma unroll
    for (int rt = 0; rt < 7; ++rt) {
        floatx4 acc = {0.f, 0.f, 0.f, 0.f};
        #pragma unroll
        for (int c = 0; c < 3; ++c) {
            short8 bf = ld8(relc + (rt*16 + col)*96 + c*32 + quad*8);
            acc = MFMA16(aq[c], bf, acc);
        }
        #pragma unroll
        for (int reg = 0; reg < 4; ++reg)
            W[quad*4 + reg][rt*16 + col] = f2s(acc[reg]);
    }

    // gather: compact E into eh (cols 232..259): eh[r][ky]=EH, eh[r][14+kx]=EW
    {
        int grow = lane & 15;
        int gq2  = q0 + grow;
        int gj0  = (gq2 > 0) ? (gq2 - 1) : 0;
        int gqy  = gj0 / QW, gqx = gj0 % QW;
        int jb   = (lane >> 4) * 7;
        #pragma unroll
        for (int u = 0; u < 7; ++u) {
            int j = jb + u;
            int idx = (j < 14) ? (gqy - 2*j + 26) : (54 + gqx - 2*(j-14) + 26);
            W[grow][232 + j] = W[grow][idx];
        }
    }

    // per-row CLS masks
    // fused S = Q K^T (scale pre-folded) + rel bias + exp -> P (cols 0..207)
    const short* kbase = kb + (long)bh*NKP*96;
    #pragma unroll
    for (int kt = 0; kt < 13; ++kt) {
        floatx4 acc = {0.f, 0.f, 0.f, 0.f};
        #pragma unroll
        for (int c = 0; c < 3; ++c) {
            short8 bf = ld8(kbase + (kt*16 + col)*96 + c*32 + quad*8);
            acc = MFMA16(aq[c], bf, acc);
        }
        int k  = kt*16 + col;
        int kk = (k > 0) ? (k - 1) : 0;
        int ky = kk / 14;  ky = (ky < 13) ? ky : 13;
        int kx = kk - 14*ky;
        #pragma unroll
        for (int reg = 0; reg < 4; ++reg) {
            int row = quad*4 + reg;
            float bias = s2f(W[row][232 + ky]) + s2f(W[row][246 + kx]);
            if (kt == 0) bias = (col == 0) ? 0.f : bias;              // CLS col
            if (q0 == 0 && reg == 0) bias = (quad == 0) ? 0.f : bias; // CLS row
            W[row][k] = f2s(__expf(acc[reg] + bias));
        }
    }
    #pragma unroll
    for (int reg = 0; reg < 4; ++reg)      // zero PV pad cols 208..223
        W[quad*4 + reg][208 + col] = 0;

    // O = P V  (7 K-chunks of 32; 6 V n-tiles + 1 ones-row n-tile = row sums)
    floatx4 o[7];
    #pragma unroll
    for (int nt = 0; nt < 7; ++nt) o[nt] = floatx4{0.f, 0.f, 0.f, 0.f};
    const short* vbase = vt + (long)bh*VROWS*NKPV;
    #pragma unroll
    for (int c = 0; c < 7; ++c) {
        short8 ap = ld8(&W[col][c*32 + quad*8]);
        #pragma unroll
        for (int nt = 0; nt < 7; ++nt) {
            short8 bf = ld8(vbase + (nt*16 + col)*NKPV + c*32 + quad*8);
            o[nt] = MFMA16(ap, bf, o[nt]);
        }
    }

    // epilogue: broadcast row sum, normalize, + residual, store
    float inv[4];
    #pragma unroll
    for (int reg = 0; reg < 4; ++reg) {
        float srow = __shfl(o[6][reg], lane & 48, 64);
        inv[reg] = 1.0f / srow;
    }
    int b = bh >> 1, h = bh & 1;
    #pragma unroll
    for (int nt = 0; nt < 6; ++nt) {
        int ch = nt*16 + col;
        #pragma unroll
        for (int reg = 0; reg < 4; ++reg) {
            int q = q0 + quad*4 + reg;
            if (q < NQ) {
                float val = o[nt][reg] * inv[reg];
                if (q > 0) val += s2f(qb[((long)bh*NQP + q)*96 + ch]);
                out[((long)b*NQ + q)*192 + h*96 + ch] = val;
            }
        }
    }
}

// ---------------------------------------------------------------------------
extern "C" void kernel_launch(void* const* d_in, const int* in_sizes, int n_in,
                              void* d_out, int out_size, void* d_ws, size_t ws_size,
                              hipStream_t stream)
{
    const float* hs    = (const float*)d_in[0];
    const float* Wq    = (const float*)d_in[1];
    const float* bq    = (const float*)d_in[2];
    const float* Wk    = (const float*)d_in[3];
    const float* bk    = (const float*)d_in[4];
    const float* Wv    = (const float*)d_in[5];
    const float* bv    = (const float*)d_in[6];
    const float* pqw   = (const float*)d_in[7];
    const float* pkw   = (const float*)d_in[8];
    const float* pvw   = (const float*)d_in[9];
    const float* gq    = (const float*)d_in[10];
    const float* betaq = (const float*)d_in[11];
    const float* gk    = (const float*)d_in[12];
    const float* betak = (const float*)d_in[13];
    const float* gv    = (const float*)d_in[14];
    const float* betav = (const float*)d_in[15];
    const float* relh  = (const float*)d_in[16];
    const float* relw  = (const float*)d_in[17];
    float* out = (float*)d_out;

    // workspace carve (bf16 as short) — ~31 MB
    short* qb   = (short*)d_ws;                  // [128][800][96]
    short* kb   = qb  + (long)128*NQP*96;        // [128][208][96]
    short* vt   = kb  + (long)128*NKP*96;        // [128][112][224]
    short* WTq  = vt  + (long)128*VROWS*NKPV;    // [192][96]
    short* WTk  = WTq + 192*96;
    short* WTv  = WTk + 192*96;
    short* relc = WTv + 192*96;                  // [112][96]
    float* cwqT = (float*)(relc + 112*96);       // [9][96] fp32
    float* cwkT = cwqT + 9*96;
    float* cwvT = cwkT + 9*96;

    prep_kernel<<<2829, 256, 0, stream>>>(Wq, Wk, Wv, relh, relw,
                                          pqw, pkw, pvw,
                                          WTq, WTk, WTv, relc, vt,
                                          cwqT, cwkT, cwvT);

    pool_proj_kernel<<<4032, 256, 0, stream>>>(
        hs, cwqT, cwkT, cwvT, gq, betaq, gk, betak, gv, betav,
        WTq, WTk, WTv, bq, bk, bv, qb, kb, vt);

    attn_kernel<<<3200, 128, 0, stream>>>(qb, kb, vt, relc, out);
}